// Round 6
// baseline (304.003 us; speedup 1.0000x reference)
//
#include <hip/hip_runtime.h>
#include <math.h>

#define LL 2048
#define CC 128
#define BB 16
#define UU 40
#define NT 256
#define NW 4
#define EPSF 1e-5f

// ---------------- reduction helpers ----------------
__device__ __forceinline__ float waveSum(float v) {
#pragma unroll
    for (int off = 1; off < 64; off <<= 1) v += __shfl_xor(v, off, 64);
    return v;
}
__device__ __forceinline__ float waveMax(float v) {
#pragma unroll
    for (int off = 1; off < 64; off <<= 1) v = fmaxf(v, __shfl_xor(v, off, 64));
    return v;
}
__device__ __forceinline__ float waveMin(float v) {
#pragma unroll
    for (int off = 1; off < 64; off <<= 1) v = fminf(v, __shfl_xor(v, off, 64));
    return v;
}
__device__ __forceinline__ float blockSum(float v, volatile float* scr) {
    v = waveSum(v);
    const int lane = threadIdx.x & 63, wid = threadIdx.x >> 6;
    __syncthreads();
    if (lane == 0) scr[wid] = v;
    __syncthreads();
    return scr[0] + scr[1] + scr[2] + scr[3];
}
__device__ __forceinline__ float blockMax(float v, volatile float* scr) {
    v = waveMax(v);
    const int lane = threadIdx.x & 63, wid = threadIdx.x >> 6;
    __syncthreads();
    if (lane == 0) scr[wid] = v;
    __syncthreads();
    return fmaxf(fmaxf(scr[0], scr[1]), fmaxf(scr[2], scr[3]));
}
__device__ __forceinline__ float blockMin(float v, volatile float* scr) {
    v = waveMin(v);
    const int lane = threadIdx.x & 63, wid = threadIdx.x >> 6;
    __syncthreads();
    if (lane == 0) scr[wid] = v;
    __syncthreads();
    return fminf(fminf(scr[0], scr[1]), fminf(scr[2], scr[3]));
}

// ---------------- idx transpose: idx[L][U] -> idxT[U][L] ----------------
__global__ __launch_bounds__(256) void transpose_idx(const int* __restrict__ idx,
                                                     int* __restrict__ idxT) {
    __shared__ int s[64 * UU];
    const int l0 = blockIdx.x * 64;
    const int tid = threadIdx.x;
    for (int e = tid; e < 64 * UU; e += 256) s[e] = idx[l0 * UU + e];
    __syncthreads();
    for (int e = tid; e < 64 * UU; e += 256) {
        const int u = e >> 6, ll = e & 63;
        idxT[u * LL + l0 + ll] = s[ll * UU + u];
    }
}

// ---------------- x transpose: x[B,L,C] -> xT[B,C,L] ----------------
__global__ __launch_bounds__(256) void transpose_in(const float* __restrict__ in,
                                                    float* __restrict__ outp) {
    __shared__ float t[32][33];
    const int b  = blockIdx.z;
    const int c0 = blockIdx.x * 32, l0 = blockIdx.y * 32;
    const int lx = threadIdx.x, ly = threadIdx.y;
    const float* base = in + ((size_t)b * LL + l0) * CC + c0;
#pragma unroll
    for (int i = 0; i < 4; ++i) t[ly + i * 8][lx] = base[(size_t)(ly + i * 8) * CC + lx];
    __syncthreads();
    float* obase = outp + ((size_t)b * CC + c0) * LL + l0;
#pragma unroll
    for (int i = 0; i < 4; ++i) obase[(size_t)(ly + i * 8) * LL + lx] = t[lx][ly + i * 8];
}
// outT [B,C,L] -> out [B,L,C]
__global__ __launch_bounds__(256) void transpose_out(const float* __restrict__ in,
                                                     float* __restrict__ outp) {
    __shared__ float t[32][33];
    const int b  = blockIdx.z;
    const int l0 = blockIdx.x * 32, c0 = blockIdx.y * 32;
    const int lx = threadIdx.x, ly = threadIdx.y;
    const float* base = in + ((size_t)b * CC + c0) * LL + l0;
#pragma unroll
    for (int i = 0; i < 4; ++i) t[ly + i * 8][lx] = base[(size_t)(ly + i * 8) * LL + lx];
    __syncthreads();
    float* obase = outp + ((size_t)b * LL + l0) * CC + c0;
#pragma unroll
    for (int i = 0; i < 4; ++i) obase[(size_t)(ly + i * 8) * CC + lx] = t[lx][ly + i * 8];
}

// ---------------- main kernel: everything per (b,c), M inline ----------------
__global__ __launch_bounds__(NT) void informer_main(
    const float* __restrict__ xT,    // [B,C,L]
    const int*   __restrict__ idxT,  // [U,L]
    float* __restrict__ outT,        // [B,C,L]
    const float* __restrict__ gWq, const float* __restrict__ gbq,
    const float* __restrict__ gWk, const float* __restrict__ gbk,
    const float* __restrict__ gWv, const float* __restrict__ gbv,
    const float* __restrict__ gWo, const float* __restrict__ gbo,
    const float* __restrict__ gw1, const float* __restrict__ gb1,
    const float* __restrict__ gw2, const float* __restrict__ gb2,
    const float* __restrict__ gg1, const float* __restrict__ gbe1,
    const float* __restrict__ gg2, const float* __restrict__ gbe2)
{
    const int tid = threadIdx.x;
    const int ln  = tid & 63;
    const int wid = tid >> 6;
    const int blk = blockIdx.x;      // b*CC + c
    const int b   = blk >> 7;
    const int c   = blk & (CC - 1);

    __shared__ __align__(16) float s_xc[LL];
    __shared__ __align__(16) float s_wk[LL];
    __shared__ float s_red[NW];
    __shared__ float s_cv[NW * UU];
    __shared__ int   s_ci[NW * UU];
    __shared__ int   s_top[UU];
    __shared__ float s_upd[UU];

    const float Wq = *gWq, bq = *gbq, Wk = *gWk, bk = *gbk;
    const float Wv = *gWv, bv = *gbv, Wo = *gWo, bo = *gbo;
    const float w1 = *gw1, b1 = *gb1, w2 = *gw2, b2 = *gb2;
    const float g1 = *gg1, be1 = *gbe1, g2 = *gg2, be2 = *gbe2;

    const float4* xrow4 = (const float4*)(xT + ((size_t)b * CC + c) * LL);
    float4* orow4 = (float4*)(outT + ((size_t)b * CC + c) * LL);
    float4* s_xc4 = (float4*)s_xc;
    float4* s_wk4 = (float4*)s_wk;

    // ---- step 1: stage x row into LDS; reduce vsum, kmin, kmax (k,v transient)
    float vsum = 0.f, kmn = 3.4e38f, kmx = -3.4e38f;
#pragma unroll
    for (int m = 0; m < 2; ++m) {
        const int f = tid + m * 256;
        float4 xv = xrow4[f];
        s_xc4[f] = xv;
        float k0 = __fadd_rn(__fmul_rn(xv.x, Wk), bk);
        float k1 = __fadd_rn(__fmul_rn(xv.y, Wk), bk);
        float k2 = __fadd_rn(__fmul_rn(xv.z, Wk), bk);
        float k3 = __fadd_rn(__fmul_rn(xv.w, Wk), bk);
        float v0 = __fadd_rn(__fmul_rn(xv.x, Wv), bv);
        float v1 = __fadd_rn(__fmul_rn(xv.y, Wv), bv);
        float v2 = __fadd_rn(__fmul_rn(xv.z, Wv), bv);
        float v3 = __fadd_rn(__fmul_rn(xv.w, Wv), bv);
        vsum += v0 + v1 + v2 + v3;
        kmx = fmaxf(kmx, fmaxf(fmaxf(k0, k1), fmaxf(k2, k3)));
        kmn = fminf(kmn, fminf(fminf(k0, k1), fminf(k2, k3)));
    }
    const float vmean  = blockSum(vsum, s_red) * (1.f / (float)LL);
    const float kmxAll = blockMax(kmx, s_red);
    const float kmnAll = blockMin(kmn, s_red);
    // (barriers inside the reducers also made s_xc visible to all waves)

    // ---- step 2: M[l] inline. l = wid*512 + ln + 64*j. idxT reads coalesced;
    // x-gathers from LDS; monotone-affine aggregates mirror the validated agg.
    const int lbase = wid * 512 + ln;
    float  mxl[8], mnl[8];
    double sml[8];
#pragma unroll
    for (int j = 0; j < 8; ++j) { mxl[j] = -3.4e38f; mnl[j] = 3.4e38f; sml[j] = 0.0; }
    const int* irow = idxT + lbase;
    for (int u = 0; u < UU; ++u) {
        const int* ru = irow + u * LL;
#pragma unroll
        for (int j = 0; j < 8; ++j) {
            const int i = ru[64 * j];
            const float xv = s_xc[i];
            mxl[j] = fmaxf(mxl[j], xv);
            mnl[j] = fminf(mnl[j], xv);
            sml[j] += (double)xv;
        }
    }
    float mloc[8];
#pragma unroll
    for (int j = 0; j < 8; ++j) {
        const float xo = s_xc[lbase + 64 * j];
        const float xH = (Wk >= 0.f) ? mxl[j] : mnl[j];
        const float xL = (Wk >= 0.f) ? mnl[j] : mxl[j];
        const float kH = __fadd_rn(__fmul_rn(xH, Wk), bk);   // = max_u k, bit-exact
        const float kL = __fadd_rn(__fmul_rn(xL, Wk), bk);   // = min_u k, bit-exact
        const float q  = __fadd_rn(__fmul_rn(xo, Wq), bq);
        const float t1 = __fmul_rn(q, (q >= 0.f) ? kH : kL); // = max_u f32(q*k_u)
        const double ks = (double)Wk * sml[j] + 40.0 * (double)bk;
        const float t2 = (float)(((double)q * ks) * (1.0 / 2048.0));
        mloc[j] = __fsub_rn(t1, t2);
    }

    // ---- step 3a: per-wave top-40 via shuffles (no block barriers)
    float wbv = mloc[0]; int wbi = lbase;
#pragma unroll
    for (int j = 1; j < 8; ++j)
        if (mloc[j] > wbv) { wbv = mloc[j]; wbi = lbase + 64 * j; }

    for (int t = 0; t < UU; ++t) {
        float rv = wbv; int ri = wbi;
#pragma unroll
        for (int off = 1; off < 64; off <<= 1) {
            float ov = __shfl_xor(rv, off, 64);
            int   oi = __shfl_xor(ri, off, 64);
            if (ov > rv || (ov == rv && oi < ri)) { rv = ov; ri = oi; }
        }
        if (ln == 0) { s_cv[wid * UU + t] = rv; s_ci[wid * UU + t] = ri; }
        if (wbi == ri) {   // owner: invalidate + rescan
#pragma unroll
            for (int j = 0; j < 8; ++j) if (lbase + 64 * j == ri) mloc[j] = -3.4e38f;
            wbv = mloc[0]; wbi = lbase;
#pragma unroll
            for (int j = 1; j < 8; ++j)
                if (mloc[j] > wbv) { wbv = mloc[j]; wbi = lbase + 64 * j; }
        }
    }
    __syncthreads();

    // ---- step 3b: merge 4x40 candidates -> global top-40 (wave 0)
    if (wid == 0) {
        float c0v = s_cv[ln],      c1v = s_cv[ln + 64];
        int   c0i = s_ci[ln],      c1i = s_ci[ln + 64];
        float c2v = (ln < 32) ? s_cv[ln + 128] : -3.4e38f;
        int   c2i = (ln < 32) ? s_ci[ln + 128] : (LL + 1);
        for (int t = 0; t < UU; ++t) {
            float rv = c0v; int ri = c0i;
            if (c1v > rv || (c1v == rv && c1i < ri)) { rv = c1v; ri = c1i; }
            if (c2v > rv || (c2v == rv && c2i < ri)) { rv = c2v; ri = c2i; }
#pragma unroll
            for (int off = 1; off < 64; off <<= 1) {
                float ov = __shfl_xor(rv, off, 64);
                int   oi = __shfl_xor(ri, off, 64);
                if (ov > rv || (ov == rv && oi < ri)) { rv = ov; ri = oi; }
            }
            if (ln == 0) s_top[t] = ri;
            if (c0i == ri) c0v = -3.4e38f;
            else if (c1i == ri) c1v = -3.4e38f;
            else if (c2i == ri) c2v = -3.4e38f;
        }
    }
    __syncthreads();

    // ---- step 4: upd[u] = softmax(q_p * k) . v — k,v recomputed from s_xc
    for (int r = 0; r < UU / NW; ++r) {
        const int u = r * NW + wid;
        const int p = s_top[u];
        const float qp = __fadd_rn(__fmul_rn(s_xc[p], Wq), bq);
        const float smax = (qp >= 0.f) ? __fmul_rn(qp, kmxAll) : __fmul_rn(qp, kmnAll);
        float se = 0.f, sev = 0.f;
#pragma unroll
        for (int m = 0; m < 8; ++m) {
            float4 xv = s_xc4[ln + m * 64];
            float k0 = __fadd_rn(__fmul_rn(xv.x, Wk), bk);
            float k1 = __fadd_rn(__fmul_rn(xv.y, Wk), bk);
            float k2 = __fadd_rn(__fmul_rn(xv.z, Wk), bk);
            float k3 = __fadd_rn(__fmul_rn(xv.w, Wk), bk);
            float e0 = __expf(__fsub_rn(__fmul_rn(qp, k0), smax));
            float e1 = __expf(__fsub_rn(__fmul_rn(qp, k1), smax));
            float e2 = __expf(__fsub_rn(__fmul_rn(qp, k2), smax));
            float e3 = __expf(__fsub_rn(__fmul_rn(qp, k3), smax));
            float v0 = __fadd_rn(__fmul_rn(xv.x, Wv), bv);
            float v1 = __fadd_rn(__fmul_rn(xv.y, Wv), bv);
            float v2 = __fadd_rn(__fmul_rn(xv.z, Wv), bv);
            float v3 = __fadd_rn(__fmul_rn(xv.w, Wv), bv);
            se += e0 + e1 + e2 + e3;
            sev = fmaf(e0, v0, fmaf(e1, v1, fmaf(e2, v2, fmaf(e3, v3, sev))));
        }
        se  = waveSum(se);
        sev = waveSum(sev);
        if (ln == 0) s_upd[u] = sev / se;
    }
    __syncthreads();

    // ---- step 5: ctx = vmean, scatter upd
#pragma unroll
    for (int m = 0; m < 2; ++m)
        s_wk4[tid + m * 256] = make_float4(vmean, vmean, vmean, vmean);
    __syncthreads();
    if (tid < UU) s_wk[s_top[tid]] = s_upd[tid];
    __syncthreads();

    // ---- step 6: t = xc + ctx*Wo + bo; LN1
    float lsum = 0.f;
#pragma unroll
    for (int m = 0; m < 2; ++m) {
        const int f = tid + m * 256;
        float4 cx = s_wk4[f], xc = s_xc4[f], tv;
        tv.x = xc.x + __fadd_rn(__fmul_rn(cx.x, Wo), bo);
        tv.y = xc.y + __fadd_rn(__fmul_rn(cx.y, Wo), bo);
        tv.z = xc.z + __fadd_rn(__fmul_rn(cx.z, Wo), bo);
        tv.w = xc.w + __fadd_rn(__fmul_rn(cx.w, Wo), bo);
        s_wk4[f] = tv;
        lsum += tv.x + tv.y + tv.z + tv.w;
    }
    const float mean1 = blockSum(lsum, s_red) * (1.f / (float)LL);
    float lss = 0.f;
#pragma unroll
    for (int m = 0; m < 2; ++m) {
        float4 tv = s_wk4[tid + m * 256];
        float d0 = tv.x - mean1, d1 = tv.y - mean1, d2 = tv.z - mean1, d3 = tv.w - mean1;
        lss += d0 * d0 + d1 * d1 + d2 * d2 + d3 * d3;
    }
    const float var1 = blockSum(lss, s_red) * (1.f / (float)LL);
    const float rs1 = rsqrtf(var1 + EPSF);

    // ---- step 7: x1 -> gelu FFN -> z; LN2 -> out
    float lsum2 = 0.f;
#pragma unroll
    for (int m = 0; m < 2; ++m) {
        const int f = tid + m * 256;
        float4 tv = s_wk4[f], zz;
        {
            float x1 = (tv.x - mean1) * rs1 * g1 + be1;
            float a = x1 * w1 + b1;
            float y = 0.5f * a * (1.f + erff(a * 0.70710678118654752f));
            zz.x = x1 + (y * w2 + b2);
        }
        {
            float x1 = (tv.y - mean1) * rs1 * g1 + be1;
            float a = x1 * w1 + b1;
            float y = 0.5f * a * (1.f + erff(a * 0.70710678118654752f));
            zz.y = x1 + (y * w2 + b2);
        }
        {
            float x1 = (tv.z - mean1) * rs1 * g1 + be1;
            float a = x1 * w1 + b1;
            float y = 0.5f * a * (1.f + erff(a * 0.70710678118654752f));
            zz.z = x1 + (y * w2 + b2);
        }
        {
            float x1 = (tv.w - mean1) * rs1 * g1 + be1;
            float a = x1 * w1 + b1;
            float y = 0.5f * a * (1.f + erff(a * 0.70710678118654752f));
            zz.w = x1 + (y * w2 + b2);
        }
        s_wk4[f] = zz;
        lsum2 += zz.x + zz.y + zz.z + zz.w;
    }
    const float mean2 = blockSum(lsum2, s_red) * (1.f / (float)LL);
    float lss2 = 0.f;
#pragma unroll
    for (int m = 0; m < 2; ++m) {
        float4 zz = s_wk4[tid + m * 256];
        float d0 = zz.x - mean2, d1 = zz.y - mean2, d2 = zz.z - mean2, d3 = zz.w - mean2;
        lss2 += d0 * d0 + d1 * d1 + d2 * d2 + d3 * d3;
    }
    const float var2 = blockSum(lss2, s_red) * (1.f / (float)LL);
    const float rs2 = rsqrtf(var2 + EPSF);

#pragma unroll
    for (int m = 0; m < 2; ++m) {
        const int f = tid + m * 256;
        float4 zz = s_wk4[f], oo;
        oo.x = (zz.x - mean2) * rs2 * g2 + be2;
        oo.y = (zz.y - mean2) * rs2 * g2 + be2;
        oo.z = (zz.z - mean2) * rs2 * g2 + be2;
        oo.w = (zz.w - mean2) * rs2 * g2 + be2;
        orow4[f] = oo;
    }
}

// ---------------- fallback (strided, self-contained; only if ws too small) ----------------
__global__ __launch_bounds__(NT) void informer_fallback(
    const float* __restrict__ xin,
    const float* __restrict__ gWq, const float* __restrict__ gbq,
    const float* __restrict__ gWk, const float* __restrict__ gbk,
    const float* __restrict__ gWv, const float* __restrict__ gbv,
    const float* __restrict__ gWo, const float* __restrict__ gbo,
    const float* __restrict__ gw1, const float* __restrict__ gb1,
    const float* __restrict__ gw2, const float* __restrict__ gb2,
    const float* __restrict__ gg1, const float* __restrict__ gbe1,
    const float* __restrict__ gg2, const float* __restrict__ gbe2,
    const int* __restrict__ idx,
    float* __restrict__ outp)
{
    const int tid  = threadIdx.x;
    const int lane = tid & 63;
    const int wid  = tid >> 6;
    const int blk  = blockIdx.x;
    const int b    = blk >> 7;
    const int c    = blk & (CC - 1);

    __shared__ float  s_xc[LL];
    __shared__ float  s_kc[LL];
    __shared__ float  s_v[LL];
    __shared__ float  s_red[NW];
    __shared__ double s_cv[NW * UU];
    __shared__ int    s_ci[NW * UU];
    __shared__ int    s_top[UU];
    __shared__ float  s_upd[UU];

    const float Wq = *gWq, bq = *gbq, Wk = *gWk, bk = *gbk;
    const float Wv = *gWv, bv = *gbv, Wo = *gWo, bo = *gbo;
    const float w1 = *gw1, b1 = *gb1, w2 = *gw2, b2 = *gb2;
    const float g1 = *gg1, be1 = *gbe1, g2 = *gg2, be2 = *gbe2;

    const float* xrow = xin + (size_t)b * LL * CC + c;
    float* orow = outp + (size_t)b * LL * CC + c;

    float vsum = 0.f, kmn = 3.4e38f, kmx = -3.4e38f;
    for (int l = tid; l < LL; l += NT) {
        float xv = xrow[(size_t)l * CC];
        s_xc[l] = xv;
        float kvv = __fadd_rn(__fmul_rn(xv, Wk), bk);
        float vvv = __fadd_rn(__fmul_rn(xv, Wv), bv);
        s_kc[l] = kvv;
        s_v[l] = vvv;
        vsum += vvv;
        kmn = fminf(kmn, kvv);
        kmx = fmaxf(kmx, kvv);
    }
    const float vmean  = blockSum(vsum, s_red) * (1.f / (float)LL);
    const float kmxAll = blockMax(kmx, s_red);
    const float kmnAll = blockMin(kmn, s_red);

    double mloc[8];
#pragma unroll
    for (int j = 0; j < 8; ++j) {
        const int l = tid + NT * j;
        const float qv = __fadd_rn(__fmul_rn(s_xc[l], Wq), bq);
        const double qd = (double)qv;
        const int* row = idx + l * UU;
        float kmaxs = -3.4e38f, kmins = 3.4e38f;
        double ssum = 0.0;
#pragma unroll 8
        for (int u = 0; u < UU; ++u) {
            float kvv = s_kc[row[u]];
            kmaxs = fmaxf(kmaxs, kvv);
            kmins = fminf(kmins, kvv);
            ssum += (double)kvv;
        }
        double qmax = (qd >= 0.0) ? qd * (double)kmaxs : qd * (double)kmins;
        mloc[j] = qmax - qd * ssum * (1.0 / (double)LL);
    }

    double wbv = mloc[0]; int wbi = tid;
#pragma unroll
    for (int j = 1; j < 8; ++j)
        if (mloc[j] > wbv) { wbv = mloc[j]; wbi = tid + NT * j; }

    for (int t = 0; t < UU; ++t) {
        double rv = wbv; int ri = wbi;
#pragma unroll
        for (int off = 1; off < 64; off <<= 1) {
            double ov = __shfl_xor(rv, off, 64);
            int    oi = __shfl_xor(ri, off, 64);
            if (ov > rv || (ov == rv && oi < ri)) { rv = ov; ri = oi; }
        }
        if (lane == 0) { s_cv[wid * UU + t] = rv; s_ci[wid * UU + t] = ri; }
        if (wbi == ri) {
#pragma unroll
            for (int j = 0; j < 8; ++j) if ((tid + NT * j) == ri) mloc[j] = -1e300;
            wbv = mloc[0]; wbi = tid;
#pragma unroll
            for (int j = 1; j < 8; ++j)
                if (mloc[j] > wbv) { wbv = mloc[j]; wbi = tid + NT * j; }
        }
    }
    __syncthreads();

    if (wid == 0) {
        double c0v = s_cv[lane], c1v = s_cv[lane + 64];
        int    c0i = s_ci[lane], c1i = s_ci[lane + 64];
        double c2v = (lane < 32) ? s_cv[lane + 128] : -1e300;
        int    c2i = (lane < 32) ? s_ci[lane + 128] : (LL + 1);
        for (int t = 0; t < UU; ++t) {
            double rv = c0v; int ri = c0i;
            if (c1v > rv || (c1v == rv && c1i < ri)) { rv = c1v; ri = c1i; }
            if (c2v > rv || (c2v == rv && c2i < ri)) { rv = c2v; ri = c2i; }
#pragma unroll
            for (int off = 1; off < 64; off <<= 1) {
                double ov = __shfl_xor(rv, off, 64);
                int    oi = __shfl_xor(ri, off, 64);
                if (ov > rv || (ov == rv && oi < ri)) { rv = ov; ri = oi; }
            }
            if (lane == 0) s_top[t] = ri;
            if (c0i == ri) c0v = -1e300;
            else if (c1i == ri) c1v = -1e300;
            else if (c2i == ri) c2v = -1e300;
        }
    }
    __syncthreads();

    for (int r = 0; r < UU / NW; ++r) {
        const int u = r * NW + wid;
        const int p = s_top[u];
        const float qp = __fadd_rn(__fmul_rn(s_xc[p], Wq), bq);
        const float smax = (qp >= 0.f) ? qp * kmxAll : qp * kmnAll;
        float se = 0.f, sev = 0.f;
        for (int l = lane; l < LL; l += 64) {
            float e = __expf(qp * s_kc[l] - smax);
            se += e;
            sev = fmaf(e, s_v[l], sev);
        }
        se = waveSum(se); sev = waveSum(sev);
        if (lane == 0) s_upd[u] = sev / se;
    }
    __syncthreads();

    for (int l = tid; l < LL; l += NT) s_kc[l] = vmean;
    __syncthreads();
    if (tid < UU) s_kc[s_top[tid]] = s_upd[tid];
    __syncthreads();

    float lsum = 0.f;
    for (int l = tid; l < LL; l += NT) {
        float tv = s_xc[l] + __fadd_rn(__fmul_rn(s_kc[l], Wo), bo);
        s_kc[l] = tv;
        lsum += tv;
    }
    const float mean1 = blockSum(lsum, s_red) * (1.f / (float)LL);
    float lss = 0.f;
    for (int l = tid; l < LL; l += NT) { float d = s_kc[l] - mean1; lss += d * d; }
    const float var1 = blockSum(lss, s_red) * (1.f / (float)LL);
    const float rs1 = rsqrtf(var1 + EPSF);

    float lsum2 = 0.f;
    for (int l = tid; l < LL; l += NT) {
        float x1 = (s_kc[l] - mean1) * rs1 * g1 + be1;
        float a  = x1 * w1 + b1;
        float y  = 0.5f * a * (1.f + erff(a * 0.70710678118654752f));
        y = y * w2 + b2;
        float z = x1 + y;
        s_kc[l] = z;
        lsum2 += z;
    }
    const float mean2 = blockSum(lsum2, s_red) * (1.f / (float)LL);
    float lss2 = 0.f;
    for (int l = tid; l < LL; l += NT) { float d = s_kc[l] - mean2; lss2 += d * d; }
    const float var2 = blockSum(lss2, s_red) * (1.f / (float)LL);
    const float rs2 = rsqrtf(var2 + EPSF);

    for (int l = tid; l < LL; l += NT)
        orow[(size_t)l * CC] = (s_kc[l] - mean2) * rs2 * g2 + be2;
}

extern "C" void kernel_launch(void* const* d_in, const int* in_sizes, int n_in,
                              void* d_out, int out_size, void* d_ws, size_t ws_size,
                              hipStream_t stream) {
    const float* x   = (const float*)d_in[0];
    const float* Wq  = (const float*)d_in[1];
    const float* bq  = (const float*)d_in[2];
    const float* Wk  = (const float*)d_in[3];
    const float* bk  = (const float*)d_in[4];
    const float* Wv  = (const float*)d_in[5];
    const float* bv  = (const float*)d_in[6];
    const float* Wo  = (const float*)d_in[7];
    const float* bo  = (const float*)d_in[8];
    const float* w1  = (const float*)d_in[9];
    const float* b1  = (const float*)d_in[10];
    const float* w2  = (const float*)d_in[11];
    const float* b2  = (const float*)d_in[12];
    const float* g1  = (const float*)d_in[13];
    const float* be1 = (const float*)d_in[14];
    const float* g2  = (const float*)d_in[15];
    const float* be2 = (const float*)d_in[16];
    const int*   idx = (const int*)d_in[17];
    float* out = (float*)d_out;

    const size_t SZ = (size_t)BB * LL * CC * sizeof(float);  // 16 MB

    if (ws_size >= 2 * SZ) {
        float* xT   = (float*)d_ws;
        float* outT = (float*)((char*)d_ws + SZ);
        int*   idxT = (int*)d_out;   // 320 KB scratch at head of d_out; main only
                                     // reads it; transpose_out overwrites d_out last.
        transpose_idx<<<dim3(LL / 64), dim3(256), 0, stream>>>(idx, idxT);
        transpose_in<<<dim3(CC / 32, LL / 32, BB), dim3(32, 8), 0, stream>>>(x, xT);
        informer_main<<<dim3(BB * CC), dim3(NT), 0, stream>>>(
            xT, idxT, outT, Wq, bq, Wk, bk, Wv, bv, Wo, bo, w1, b1, w2, b2,
            g1, be1, g2, be2);
        transpose_out<<<dim3(LL / 32, CC / 32, BB), dim3(32, 8), 0, stream>>>(outT, out);
    } else {
        informer_fallback<<<dim3(BB * CC), dim3(NT), 0, stream>>>(
            x, Wq, bq, Wk, bk, Wv, bv, Wo, bo, w1, b1, w2, b2,
            g1, be1, g2, be2, idx, out);
    }
}

// Round 7
// 299.309 us; speedup vs baseline: 1.0157x; 1.0157x over previous
//
#include <hip/hip_runtime.h>
#include <math.h>

#define LL 2048
#define CC 128
#define BB 16
#define UU 40
#define NT 256
#define NW 4
#define EPSF 1e-5f

// ---------------- reduction helpers ----------------
__device__ __forceinline__ float waveSum(float v) {
#pragma unroll
    for (int off = 1; off < 64; off <<= 1) v += __shfl_xor(v, off, 64);
    return v;
}
__device__ __forceinline__ float waveMax(float v) {
#pragma unroll
    for (int off = 1; off < 64; off <<= 1) v = fmaxf(v, __shfl_xor(v, off, 64));
    return v;
}
__device__ __forceinline__ float waveMin(float v) {
#pragma unroll
    for (int off = 1; off < 64; off <<= 1) v = fminf(v, __shfl_xor(v, off, 64));
    return v;
}
__device__ __forceinline__ float blockSum(float v, volatile float* scr) {
    v = waveSum(v);
    const int lane = threadIdx.x & 63, wid = threadIdx.x >> 6;
    __syncthreads();
    if (lane == 0) scr[wid] = v;
    __syncthreads();
    return scr[0] + scr[1] + scr[2] + scr[3];
}
__device__ __forceinline__ float blockMax(float v, volatile float* scr) {
    v = waveMax(v);
    const int lane = threadIdx.x & 63, wid = threadIdx.x >> 6;
    __syncthreads();
    if (lane == 0) scr[wid] = v;
    __syncthreads();
    return fmaxf(fmaxf(scr[0], scr[1]), fmaxf(scr[2], scr[3]));
}
__device__ __forceinline__ float blockMin(float v, volatile float* scr) {
    v = waveMin(v);
    const int lane = threadIdx.x & 63, wid = threadIdx.x >> 6;
    __syncthreads();
    if (lane == 0) scr[wid] = v;
    __syncthreads();
    return fminf(fminf(scr[0], scr[1]), fminf(scr[2], scr[3]));
}

// ---------------- idx transpose: idx[L][U] int32 -> idxT[U][L] ushort ----------------
__global__ __launch_bounds__(256) void transpose_idx(const int* __restrict__ idx,
                                                     unsigned short* __restrict__ idxT) {
    __shared__ int s[64 * UU];
    const int l0 = blockIdx.x * 64;
    const int tid = threadIdx.x;
    for (int e = tid; e < 64 * UU; e += 256) s[e] = idx[l0 * UU + e];
    __syncthreads();
    for (int e = tid; e < 64 * UU; e += 256) {
        const int u = e >> 6, ll = e & 63;
        idxT[u * LL + l0 + ll] = (unsigned short)s[ll * UU + u];
    }
}

// ---------------- x transpose: x[B,L,C] -> xT[B,C,L] ----------------
__global__ __launch_bounds__(256) void transpose_in(const float* __restrict__ in,
                                                    float* __restrict__ outp) {
    __shared__ float t[32][33];
    const int b  = blockIdx.z;
    const int c0 = blockIdx.x * 32, l0 = blockIdx.y * 32;
    const int lx = threadIdx.x, ly = threadIdx.y;
    const float* base = in + ((size_t)b * LL + l0) * CC + c0;
#pragma unroll
    for (int i = 0; i < 4; ++i) t[ly + i * 8][lx] = base[(size_t)(ly + i * 8) * CC + lx];
    __syncthreads();
    float* obase = outp + ((size_t)b * CC + c0) * LL + l0;
#pragma unroll
    for (int i = 0; i < 4; ++i) obase[(size_t)(ly + i * 8) * LL + lx] = t[lx][ly + i * 8];
}
// outT [B,C,L] -> out [B,L,C]
__global__ __launch_bounds__(256) void transpose_out(const float* __restrict__ in,
                                                     float* __restrict__ outp) {
    __shared__ float t[32][33];
    const int b  = blockIdx.z;
    const int l0 = blockIdx.x * 32, c0 = blockIdx.y * 32;
    const int lx = threadIdx.x, ly = threadIdx.y;
    const float* base = in + ((size_t)b * CC + c0) * LL + l0;
#pragma unroll
    for (int i = 0; i < 4; ++i) t[ly + i * 8][lx] = base[(size_t)(ly + i * 8) * LL + lx];
    __syncthreads();
    float* obase = outp + ((size_t)b * LL + l0) * CC + c0;
#pragma unroll
    for (int i = 0; i < 4; ++i) obase[(size_t)(ly + i * 8) * CC + lx] = t[lx][ly + i * 8];
}

// ---------------- main kernel: everything per (b,c), M inline ----------------
__global__ __launch_bounds__(NT, 4) void informer_main(
    const float* __restrict__ xT,             // [B,C,L]
    const unsigned short* __restrict__ idxT,  // [U,L]
    float* __restrict__ outT,                 // [B,C,L]
    const float* __restrict__ gWq, const float* __restrict__ gbq,
    const float* __restrict__ gWk, const float* __restrict__ gbk,
    const float* __restrict__ gWv, const float* __restrict__ gbv,
    const float* __restrict__ gWo, const float* __restrict__ gbo,
    const float* __restrict__ gw1, const float* __restrict__ gb1,
    const float* __restrict__ gw2, const float* __restrict__ gb2,
    const float* __restrict__ gg1, const float* __restrict__ gbe1,
    const float* __restrict__ gg2, const float* __restrict__ gbe2)
{
    const int tid = threadIdx.x;
    const int ln  = tid & 63;
    const int wid = tid >> 6;
    const int blk = blockIdx.x;      // b*CC + c
    const int b   = blk >> 7;
    const int c   = blk & (CC - 1);

    __shared__ __align__(16) float s_xc[LL];
    __shared__ __align__(16) float s_wk[LL];
    __shared__ float s_red[NW];
    __shared__ float s_cv[NW * UU];
    __shared__ int   s_ci[NW * UU];
    __shared__ int   s_top[UU];
    __shared__ float s_upd[UU];

    const float Wq = *gWq, bq = *gbq, Wk = *gWk, bk = *gbk;
    const float Wv = *gWv, bv = *gbv, Wo = *gWo, bo = *gbo;
    const float w1 = *gw1, b1 = *gb1, w2 = *gw2, b2 = *gb2;
    const float g1 = *gg1, be1 = *gbe1, g2 = *gg2, be2 = *gbe2;

    const float4* xrow4 = (const float4*)(xT + ((size_t)b * CC + c) * LL);
    float4* orow4 = (float4*)(outT + ((size_t)b * CC + c) * LL);
    float4* s_xc4 = (float4*)s_xc;
    float4* s_wk4 = (float4*)s_wk;

    // ---- step 1: stage x row into LDS; reduce vsum, kmin, kmax (k,v transient)
    float vsum = 0.f, kmn = 3.4e38f, kmx = -3.4e38f;
#pragma unroll
    for (int m = 0; m < 2; ++m) {
        const int f = tid + m * 256;
        float4 xv = xrow4[f];
        s_xc4[f] = xv;
        float k0 = __fadd_rn(__fmul_rn(xv.x, Wk), bk);
        float k1 = __fadd_rn(__fmul_rn(xv.y, Wk), bk);
        float k2 = __fadd_rn(__fmul_rn(xv.z, Wk), bk);
        float k3 = __fadd_rn(__fmul_rn(xv.w, Wk), bk);
        float v0 = __fadd_rn(__fmul_rn(xv.x, Wv), bv);
        float v1 = __fadd_rn(__fmul_rn(xv.y, Wv), bv);
        float v2 = __fadd_rn(__fmul_rn(xv.z, Wv), bv);
        float v3 = __fadd_rn(__fmul_rn(xv.w, Wv), bv);
        vsum += v0 + v1 + v2 + v3;
        kmx = fmaxf(kmx, fmaxf(fmaxf(k0, k1), fmaxf(k2, k3)));
        kmn = fminf(kmn, fminf(fminf(k0, k1), fminf(k2, k3)));
    }
    const float vmean  = blockSum(vsum, s_red) * (1.f / (float)LL);
    const float kmxAll = blockMax(kmx, s_red);
    const float kmnAll = blockMin(kmn, s_red);
    // (barriers inside the reducers also made s_xc visible to all waves)

    // ---- step 2: M[l] inline, j OUTER (unrolled; 4-reg live state per j -> no spill),
    // u inner. idxT ushort reads coalesced; x gathered from LDS; monotone-affine
    // aggregates mirror the validated agg formula exactly.
    const int lbase = wid * 512 + ln;
    float mloc[8];
#pragma unroll
    for (int j = 0; j < 8; ++j) {
        const unsigned short* pj = idxT + lbase + 64 * j;
        float  mx = -3.4e38f, mn = 3.4e38f;
        double sm = 0.0;
#pragma unroll 8
        for (int u = 0; u < UU; ++u) {
            const int i = (int)pj[(size_t)u * LL];
            const float xv = s_xc[i];
            mx = fmaxf(mx, xv);
            mn = fminf(mn, xv);
            sm += (double)xv;
        }
        const float xo = s_xc[lbase + 64 * j];
        const float xH = (Wk >= 0.f) ? mx : mn;
        const float xL = (Wk >= 0.f) ? mn : mx;
        const float kH = __fadd_rn(__fmul_rn(xH, Wk), bk);   // = max_u k, bit-exact
        const float kL = __fadd_rn(__fmul_rn(xL, Wk), bk);   // = min_u k, bit-exact
        const float q  = __fadd_rn(__fmul_rn(xo, Wq), bq);
        const float t1 = __fmul_rn(q, (q >= 0.f) ? kH : kL); // = max_u f32(q*k_u)
        const double ks = (double)Wk * sm + 40.0 * (double)bk;
        const float t2 = (float)(((double)q * ks) * (1.0 / 2048.0));
        mloc[j] = __fsub_rn(t1, t2);
    }

    // ---- step 3a: per-wave top-40 via shuffles (no block barriers)
    float wbv = mloc[0]; int wbi = lbase;
#pragma unroll
    for (int j = 1; j < 8; ++j)
        if (mloc[j] > wbv) { wbv = mloc[j]; wbi = lbase + 64 * j; }

    for (int t = 0; t < UU; ++t) {
        float rv = wbv; int ri = wbi;
#pragma unroll
        for (int off = 1; off < 64; off <<= 1) {
            float ov = __shfl_xor(rv, off, 64);
            int   oi = __shfl_xor(ri, off, 64);
            if (ov > rv || (ov == rv && oi < ri)) { rv = ov; ri = oi; }
        }
        if (ln == 0) { s_cv[wid * UU + t] = rv; s_ci[wid * UU + t] = ri; }
        if (wbi == ri) {   // owner: invalidate + rescan
#pragma unroll
            for (int j = 0; j < 8; ++j) if (lbase + 64 * j == ri) mloc[j] = -3.4e38f;
            wbv = mloc[0]; wbi = lbase;
#pragma unroll
            for (int j = 1; j < 8; ++j)
                if (mloc[j] > wbv) { wbv = mloc[j]; wbi = lbase + 64 * j; }
        }
    }
    __syncthreads();

    // ---- step 3b: merge 4x40 candidates -> global top-40 (wave 0)
    if (wid == 0) {
        float c0v = s_cv[ln],      c1v = s_cv[ln + 64];
        int   c0i = s_ci[ln],      c1i = s_ci[ln + 64];
        float c2v = (ln < 32) ? s_cv[ln + 128] : -3.4e38f;
        int   c2i = (ln < 32) ? s_ci[ln + 128] : (LL + 1);
        for (int t = 0; t < UU; ++t) {
            float rv = c0v; int ri = c0i;
            if (c1v > rv || (c1v == rv && c1i < ri)) { rv = c1v; ri = c1i; }
            if (c2v > rv || (c2v == rv && c2i < ri)) { rv = c2v; ri = c2i; }
#pragma unroll
            for (int off = 1; off < 64; off <<= 1) {
                float ov = __shfl_xor(rv, off, 64);
                int   oi = __shfl_xor(ri, off, 64);
                if (ov > rv || (ov == rv && oi < ri)) { rv = ov; ri = oi; }
            }
            if (ln == 0) s_top[t] = ri;
            if (c0i == ri) c0v = -3.4e38f;
            else if (c1i == ri) c1v = -3.4e38f;
            else if (c2i == ri) c2v = -3.4e38f;
        }
    }
    __syncthreads();

    // ---- step 4: upd[u] = softmax(q_p * k) . v — k,v recomputed from s_xc
    for (int r = 0; r < UU / NW; ++r) {
        const int u = r * NW + wid;
        const int p = s_top[u];
        const float qp = __fadd_rn(__fmul_rn(s_xc[p], Wq), bq);
        const float smax = (qp >= 0.f) ? __fmul_rn(qp, kmxAll) : __fmul_rn(qp, kmnAll);
        float se = 0.f, sev = 0.f;
#pragma unroll
        for (int m = 0; m < 8; ++m) {
            float4 xv = s_xc4[ln + m * 64];
            float k0 = __fadd_rn(__fmul_rn(xv.x, Wk), bk);
            float k1 = __fadd_rn(__fmul_rn(xv.y, Wk), bk);
            float k2 = __fadd_rn(__fmul_rn(xv.z, Wk), bk);
            float k3 = __fadd_rn(__fmul_rn(xv.w, Wk), bk);
            float e0 = __expf(__fsub_rn(__fmul_rn(qp, k0), smax));
            float e1 = __expf(__fsub_rn(__fmul_rn(qp, k1), smax));
            float e2 = __expf(__fsub_rn(__fmul_rn(qp, k2), smax));
            float e3 = __expf(__fsub_rn(__fmul_rn(qp, k3), smax));
            float v0 = __fadd_rn(__fmul_rn(xv.x, Wv), bv);
            float v1 = __fadd_rn(__fmul_rn(xv.y, Wv), bv);
            float v2 = __fadd_rn(__fmul_rn(xv.z, Wv), bv);
            float v3 = __fadd_rn(__fmul_rn(xv.w, Wv), bv);
            se += e0 + e1 + e2 + e3;
            sev = fmaf(e0, v0, fmaf(e1, v1, fmaf(e2, v2, fmaf(e3, v3, sev))));
        }
        se  = waveSum(se);
        sev = waveSum(sev);
        if (ln == 0) s_upd[u] = sev / se;
    }
    __syncthreads();

    // ---- step 5: ctx = vmean, scatter upd
#pragma unroll
    for (int m = 0; m < 2; ++m)
        s_wk4[tid + m * 256] = make_float4(vmean, vmean, vmean, vmean);
    __syncthreads();
    if (tid < UU) s_wk[s_top[tid]] = s_upd[tid];
    __syncthreads();

    // ---- step 6: t = xc + ctx*Wo + bo; LN1
    float lsum = 0.f;
#pragma unroll
    for (int m = 0; m < 2; ++m) {
        const int f = tid + m * 256;
        float4 cx = s_wk4[f], xc = s_xc4[f], tv;
        tv.x = xc.x + __fadd_rn(__fmul_rn(cx.x, Wo), bo);
        tv.y = xc.y + __fadd_rn(__fmul_rn(cx.y, Wo), bo);
        tv.z = xc.z + __fadd_rn(__fmul_rn(cx.z, Wo), bo);
        tv.w = xc.w + __fadd_rn(__fmul_rn(cx.w, Wo), bo);
        s_wk4[f] = tv;
        lsum += tv.x + tv.y + tv.z + tv.w;
    }
    const float mean1 = blockSum(lsum, s_red) * (1.f / (float)LL);
    float lss = 0.f;
#pragma unroll
    for (int m = 0; m < 2; ++m) {
        float4 tv = s_wk4[tid + m * 256];
        float d0 = tv.x - mean1, d1 = tv.y - mean1, d2 = tv.z - mean1, d3 = tv.w - mean1;
        lss += d0 * d0 + d1 * d1 + d2 * d2 + d3 * d3;
    }
    const float var1 = blockSum(lss, s_red) * (1.f / (float)LL);
    const float rs1 = rsqrtf(var1 + EPSF);

    // ---- step 7: x1 -> gelu FFN -> z; LN2 -> out
    float lsum2 = 0.f;
#pragma unroll
    for (int m = 0; m < 2; ++m) {
        const int f = tid + m * 256;
        float4 tv = s_wk4[f], zz;
        {
            float x1 = (tv.x - mean1) * rs1 * g1 + be1;
            float a = x1 * w1 + b1;
            float y = 0.5f * a * (1.f + erff(a * 0.70710678118654752f));
            zz.x = x1 + (y * w2 + b2);
        }
        {
            float x1 = (tv.y - mean1) * rs1 * g1 + be1;
            float a = x1 * w1 + b1;
            float y = 0.5f * a * (1.f + erff(a * 0.70710678118654752f));
            zz.y = x1 + (y * w2 + b2);
        }
        {
            float x1 = (tv.z - mean1) * rs1 * g1 + be1;
            float a = x1 * w1 + b1;
            float y = 0.5f * a * (1.f + erff(a * 0.70710678118654752f));
            zz.z = x1 + (y * w2 + b2);
        }
        {
            float x1 = (tv.w - mean1) * rs1 * g1 + be1;
            float a = x1 * w1 + b1;
            float y = 0.5f * a * (1.f + erff(a * 0.70710678118654752f));
            zz.w = x1 + (y * w2 + b2);
        }
        s_wk4[f] = zz;
        lsum2 += zz.x + zz.y + zz.z + zz.w;
    }
    const float mean2 = blockSum(lsum2, s_red) * (1.f / (float)LL);
    float lss2 = 0.f;
#pragma unroll
    for (int m = 0; m < 2; ++m) {
        float4 zz = s_wk4[tid + m * 256];
        float d0 = zz.x - mean2, d1 = zz.y - mean2, d2 = zz.z - mean2, d3 = zz.w - mean2;
        lss2 += d0 * d0 + d1 * d1 + d2 * d2 + d3 * d3;
    }
    const float var2 = blockSum(lss2, s_red) * (1.f / (float)LL);
    const float rs2 = rsqrtf(var2 + EPSF);

#pragma unroll
    for (int m = 0; m < 2; ++m) {
        const int f = tid + m * 256;
        float4 zz = s_wk4[f], oo;
        oo.x = (zz.x - mean2) * rs2 * g2 + be2;
        oo.y = (zz.y - mean2) * rs2 * g2 + be2;
        oo.z = (zz.z - mean2) * rs2 * g2 + be2;
        oo.w = (zz.w - mean2) * rs2 * g2 + be2;
        orow4[f] = oo;
    }
}

// ---------------- fallback (strided, self-contained; only if ws too small) ----------------
__global__ __launch_bounds__(NT) void informer_fallback(
    const float* __restrict__ xin,
    const float* __restrict__ gWq, const float* __restrict__ gbq,
    const float* __restrict__ gWk, const float* __restrict__ gbk,
    const float* __restrict__ gWv, const float* __restrict__ gbv,
    const float* __restrict__ gWo, const float* __restrict__ gbo,
    const float* __restrict__ gw1, const float* __restrict__ gb1,
    const float* __restrict__ gw2, const float* __restrict__ gb2,
    const float* __restrict__ gg1, const float* __restrict__ gbe1,
    const float* __restrict__ gg2, const float* __restrict__ gbe2,
    const int* __restrict__ idx,
    float* __restrict__ outp)
{
    const int tid  = threadIdx.x;
    const int lane = tid & 63;
    const int wid  = tid >> 6;
    const int blk  = blockIdx.x;
    const int b    = blk >> 7;
    const int c    = blk & (CC - 1);

    __shared__ float  s_xc[LL];
    __shared__ float  s_kc[LL];
    __shared__ float  s_v[LL];
    __shared__ float  s_red[NW];
    __shared__ double s_cv[NW * UU];
    __shared__ int    s_ci[NW * UU];
    __shared__ int    s_top[UU];
    __shared__ float  s_upd[UU];

    const float Wq = *gWq, bq = *gbq, Wk = *gWk, bk = *gbk;
    const float Wv = *gWv, bv = *gbv, Wo = *gWo, bo = *gbo;
    const float w1 = *gw1, b1 = *gb1, w2 = *gw2, b2 = *gb2;
    const float g1 = *gg1, be1 = *gbe1, g2 = *gg2, be2 = *gbe2;

    const float* xrow = xin + (size_t)b * LL * CC + c;
    float* orow = outp + (size_t)b * LL * CC + c;

    float vsum = 0.f, kmn = 3.4e38f, kmx = -3.4e38f;
    for (int l = tid; l < LL; l += NT) {
        float xv = xrow[(size_t)l * CC];
        s_xc[l] = xv;
        float kvv = __fadd_rn(__fmul_rn(xv, Wk), bk);
        float vvv = __fadd_rn(__fmul_rn(xv, Wv), bv);
        s_kc[l] = kvv;
        s_v[l] = vvv;
        vsum += vvv;
        kmn = fminf(kmn, kvv);
        kmx = fmaxf(kmx, kvv);
    }
    const float vmean  = blockSum(vsum, s_red) * (1.f / (float)LL);
    const float kmxAll = blockMax(kmx, s_red);
    const float kmnAll = blockMin(kmn, s_red);

    double mloc[8];
#pragma unroll
    for (int j = 0; j < 8; ++j) {
        const int l = tid + NT * j;
        const float qv = __fadd_rn(__fmul_rn(s_xc[l], Wq), bq);
        const double qd = (double)qv;
        const int* row = idx + l * UU;
        float kmaxs = -3.4e38f, kmins = 3.4e38f;
        double ssum = 0.0;
#pragma unroll 8
        for (int u = 0; u < UU; ++u) {
            float kvv = s_kc[row[u]];
            kmaxs = fmaxf(kmaxs, kvv);
            kmins = fminf(kmins, kvv);
            ssum += (double)kvv;
        }
        double qmax = (qd >= 0.0) ? qd * (double)kmaxs : qd * (double)kmins;
        mloc[j] = qmax - qd * ssum * (1.0 / (double)LL);
    }

    double wbv = mloc[0]; int wbi = tid;
#pragma unroll
    for (int j = 1; j < 8; ++j)
        if (mloc[j] > wbv) { wbv = mloc[j]; wbi = tid + NT * j; }

    for (int t = 0; t < UU; ++t) {
        double rv = wbv; int ri = wbi;
#pragma unroll
        for (int off = 1; off < 64; off <<= 1) {
            double ov = __shfl_xor(rv, off, 64);
            int    oi = __shfl_xor(ri, off, 64);
            if (ov > rv || (ov == rv && oi < ri)) { rv = ov; ri = oi; }
        }
        if (lane == 0) { s_cv[wid * UU + t] = rv; s_ci[wid * UU + t] = ri; }
        if (wbi == ri) {
#pragma unroll
            for (int j = 0; j < 8; ++j) if ((tid + NT * j) == ri) mloc[j] = -1e300;
            wbv = mloc[0]; wbi = tid;
#pragma unroll
            for (int j = 1; j < 8; ++j)
                if (mloc[j] > wbv) { wbv = mloc[j]; wbi = tid + NT * j; }
        }
    }
    __syncthreads();

    if (wid == 0) {
        double c0v = s_cv[lane], c1v = s_cv[lane + 64];
        int    c0i = s_ci[lane], c1i = s_ci[lane + 64];
        double c2v = (lane < 32) ? s_cv[lane + 128] : -1e300;
        int    c2i = (lane < 32) ? s_ci[lane + 128] : (LL + 1);
        for (int t = 0; t < UU; ++t) {
            double rv = c0v; int ri = c0i;
            if (c1v > rv || (c1v == rv && c1i < ri)) { rv = c1v; ri = c1i; }
            if (c2v > rv || (c2v == rv && c2i < ri)) { rv = c2v; ri = c2i; }
#pragma unroll
            for (int off = 1; off < 64; off <<= 1) {
                double ov = __shfl_xor(rv, off, 64);
                int    oi = __shfl_xor(ri, off, 64);
                if (ov > rv || (ov == rv && oi < ri)) { rv = ov; ri = oi; }
            }
            if (lane == 0) s_top[t] = ri;
            if (c0i == ri) c0v = -1e300;
            else if (c1i == ri) c1v = -1e300;
            else if (c2i == ri) c2v = -1e300;
        }
    }
    __syncthreads();

    for (int r = 0; r < UU / NW; ++r) {
        const int u = r * NW + wid;
        const int p = s_top[u];
        const float qp = __fadd_rn(__fmul_rn(s_xc[p], Wq), bq);
        const float smax = (qp >= 0.f) ? qp * kmxAll : qp * kmnAll;
        float se = 0.f, sev = 0.f;
        for (int l = lane; l < LL; l += 64) {
            float e = __expf(qp * s_kc[l] - smax);
            se += e;
            sev = fmaf(e, s_v[l], sev);
        }
        se = waveSum(se); sev = waveSum(sev);
        if (lane == 0) s_upd[u] = sev / se;
    }
    __syncthreads();

    for (int l = tid; l < LL; l += NT) s_kc[l] = vmean;
    __syncthreads();
    if (tid < UU) s_kc[s_top[tid]] = s_upd[tid];
    __syncthreads();

    float lsum = 0.f;
    for (int l = tid; l < LL; l += NT) {
        float tv = s_xc[l] + __fadd_rn(__fmul_rn(s_kc[l], Wo), bo);
        s_kc[l] = tv;
        lsum += tv;
    }
    const float mean1 = blockSum(lsum, s_red) * (1.f / (float)LL);
    float lss = 0.f;
    for (int l = tid; l < LL; l += NT) { float d = s_kc[l] - mean1; lss += d * d; }
    const float var1 = blockSum(lss, s_red) * (1.f / (float)LL);
    const float rs1 = rsqrtf(var1 + EPSF);

    float lsum2 = 0.f;
    for (int l = tid; l < LL; l += NT) {
        float x1 = (s_kc[l] - mean1) * rs1 * g1 + be1;
        float a  = x1 * w1 + b1;
        float y  = 0.5f * a * (1.f + erff(a * 0.70710678118654752f));
        y = y * w2 + b2;
        float z = x1 + y;
        s_kc[l] = z;
        lsum2 += z;
    }
    const float mean2 = blockSum(lsum2, s_red) * (1.f / (float)LL);
    float lss2 = 0.f;
    for (int l = tid; l < LL; l += NT) { float d = s_kc[l] - mean2; lss2 += d * d; }
    const float var2 = blockSum(lss2, s_red) * (1.f / (float)LL);
    const float rs2 = rsqrtf(var2 + EPSF);

    for (int l = tid; l < LL; l += NT)
        orow[(size_t)l * CC] = (s_kc[l] - mean2) * rs2 * g2 + be2;
}

extern "C" void kernel_launch(void* const* d_in, const int* in_sizes, int n_in,
                              void* d_out, int out_size, void* d_ws, size_t ws_size,
                              hipStream_t stream) {
    const float* x   = (const float*)d_in[0];
    const float* Wq  = (const float*)d_in[1];
    const float* bq  = (const float*)d_in[2];
    const float* Wk  = (const float*)d_in[3];
    const float* bk  = (const float*)d_in[4];
    const float* Wv  = (const float*)d_in[5];
    const float* bv  = (const float*)d_in[6];
    const float* Wo  = (const float*)d_in[7];
    const float* bo  = (const float*)d_in[8];
    const float* w1  = (const float*)d_in[9];
    const float* b1  = (const float*)d_in[10];
    const float* w2  = (const float*)d_in[11];
    const float* b2  = (const float*)d_in[12];
    const float* g1  = (const float*)d_in[13];
    const float* be1 = (const float*)d_in[14];
    const float* g2  = (const float*)d_in[15];
    const float* be2 = (const float*)d_in[16];
    const int*   idx = (const int*)d_in[17];
    float* out = (float*)d_out;

    const size_t SZ = (size_t)BB * LL * CC * sizeof(float);  // 16 MB

    if (ws_size >= 2 * SZ) {
        float* xT   = (float*)d_ws;
        float* outT = (float*)((char*)d_ws + SZ);
        unsigned short* idxT = (unsigned short*)d_out;  // 160 KB scratch at head of
                                                        // d_out; overwritten last.
        transpose_idx<<<dim3(LL / 64), dim3(256), 0, stream>>>(idx, idxT);
        transpose_in<<<dim3(CC / 32, LL / 32, BB), dim3(32, 8), 0, stream>>>(x, xT);
        informer_main<<<dim3(BB * CC), dim3(NT), 0, stream>>>(
            xT, idxT, outT, Wq, bq, Wk, bk, Wv, bv, Wo, bo, w1, b1, w2, b2,
            g1, be1, g2, be2);
        transpose_out<<<dim3(LL / 32, CC / 32, BB), dim3(32, 8), 0, stream>>>(outT, out);
    } else {
        informer_fallback<<<dim3(BB * CC), dim3(NT), 0, stream>>>(
            x, Wq, bq, Wk, bk, Wv, bv, Wo, bo, w1, b1, w2, b2,
            g1, be1, g2, be2, idx, out);
    }
}